// Round 4
// baseline (749.154 us; speedup 1.0000x reference)
//
#include <hip/hip_runtime.h>
#include <hip/hip_bf16.h>
#include <math.h>

// Problem constants
#define B_ 32
#define D_ 192
#define DEPTH_ 4
#define DI_ 384
#define DS_ 16
#define DC_ 4
#define P_ 16
#define IMG_ 224
#define N_ 196
#define L_ 197

typedef short s16x8 __attribute__((ext_vector_type(8)));
typedef float f32x16 __attribute__((ext_vector_type(16)));

__device__ __forceinline__ float sigmoidf_(float x) { return 1.f / (1.f + expf(-x)); }

// ---------------- weight cast fp32 -> bf16 ----------------
__global__ void k_cast(const float* __restrict__ s, __hip_bfloat16* __restrict__ d, int n) {
  for (int i = blockIdx.x * 256 + threadIdx.x; i < n; i += gridDim.x * 256)
    d[i] = __float2bfloat16(s[i]);
}

// ---------------- cls token + pos embed (row l=0) ----------------
__global__ void k_cls(const float* __restrict__ cls_tok, const float* __restrict__ pos,
                      float* __restrict__ t) {
  int b = blockIdx.x, d = threadIdx.x;
  t[(size_t)b * L_ * D_ + d] = cls_tok[d] + pos[d];
}

// ---------------- im2col: x (B,3,224,224) -> A bf16 (6272 x 768) ----------------
__global__ __launch_bounds__(256) void k_im2col(const float* __restrict__ x,
                                                __hip_bfloat16* __restrict__ A) {
  int idx = blockIdx.x * 256 + threadIdx.x;  // grid exact: 18816*256 = 6272*768
  int tok = idx / 768, f = idx - tok * 768;
  int b = tok / 196, p = tok - b * 196;
  int h = p / 14, w = p - h * 14;
  int c = f >> 8, i = (f >> 4) & 15, j = f & 15;
  float v = x[(((size_t)(b * 3 + c) * 224 + h * 16 + i) * 224 + w * 16 + j)];
  A[idx] = __float2bfloat16(v);
}

// ---------------- generic bf16 MFMA GEMM: C[M x N] = A[M x K] @ W[N x K]^T ----------------
// block = 256 thr (4 waves), tile M64 x N64, wave tile 32x32 (mfma_f32_32x32x16_bf16)
// K-chunks of 96 staged in LDS (both operands), stride 104 to tame bank conflicts.
// MODE 0: C (stride 768) = acc                       (xz = ln(t) @ w_in^T)
// MODE 1: C (stride 192) += acc                      (t += y @ w_out^T)
// MODE 2: patch epilogue: t[(b*197+1+p)*192+n] = acc + bias[n] + pos[(1+p)*192+n]
template <int KTOT, int MODE>
__global__ __launch_bounds__(256) void k_gemm_mfma(const short* __restrict__ A,
                                                   const short* __restrict__ Wb,
                                                   float* __restrict__ C,
                                                   const float* __restrict__ bias,
                                                   const float* __restrict__ pos,
                                                   int M) {
  constexpr int KC = 96;
  constexpr int STR = 104;  // 208 B row stride -> 4-way bank conflict worst case (1.58x)
  __shared__ __align__(16) short Als[64 * STR];
  __shared__ __align__(16) short Bls[64 * STR];
  int m0 = blockIdx.x * 64, n0 = blockIdx.y * 64;
  int tid = threadIdx.x;
  int lane = tid & 63, wid = tid >> 6;
  int mw = (wid & 1) * 32, nw = (wid >> 1) * 32;
  int l31 = lane & 31, lh = lane >> 5;
  f32x16 acc;
#pragma unroll
  for (int i = 0; i < 16; i++) acc[i] = 0.f;
  for (int kc = 0; kc < KTOT; kc += KC) {
    __syncthreads();
#pragma unroll
    for (int i = 0; i < 3; i++) {
      int seg = tid + i * 256;        // 768 segments: 64 rows x 12 k-segs of 8 bf16
      int r = seg / 12, s = seg - r * 12;
      *(s16x8*)(Als + r * STR + s * 8) =
          *(const s16x8*)(A + (size_t)(m0 + r) * KTOT + kc + s * 8);
      *(s16x8*)(Bls + r * STR + s * 8) =
          *(const s16x8*)(Wb + (size_t)(n0 + r) * KTOT + kc + s * 8);
    }
    __syncthreads();
#pragma unroll
    for (int ks = 0; ks < KC / 16; ks++) {
      s16x8 af = *(const s16x8*)(Als + (mw + l31) * STR + ks * 16 + lh * 8);
      s16x8 bf = *(const s16x8*)(Bls + (nw + l31) * STR + ks * 16 + lh * 8);
      acc = __builtin_amdgcn_mfma_f32_32x32x16_bf16(af, bf, acc, 0, 0, 0);
    }
  }
  // epilogue: C/D layout col=lane&31, row=(reg&3)+8*(reg>>2)+4*(lane>>5)
  int gn = n0 + nw + l31;
#pragma unroll
  for (int i = 0; i < 16; i++) {
    int rowt = mw + (i & 3) + 8 * (i >> 2) + 4 * lh;
    int gm = m0 + rowt;
    float v = acc[i];
    if (MODE == 0) {
      if (gm < M) C[(size_t)gm * 768 + gn] = v;
    } else if (MODE == 1) {
      if (gm < M) C[(size_t)gm * 192 + gn] += v;
    } else {
      int b = gm / 196, p = gm - b * 196;
      C[((size_t)b * 197 + 1 + p) * 192 + gn] =
          v + bias[gn] + pos[(size_t)(1 + p) * 192 + gn];
    }
  }
}

// ---------------- LayerNorm per token -> bf16 out ----------------
__global__ __launch_bounds__(64) void k_ln_bf(const float* __restrict__ t,
                                              const float* __restrict__ g,
                                              const float* __restrict__ bb,
                                              __hip_bfloat16* __restrict__ o) {
  int tok = blockIdx.x, tid = threadIdx.x;
  const float* xr = t + (size_t)tok * D_;
  float x0 = xr[tid], x1 = xr[tid + 64], x2 = xr[tid + 128];
  float s = x0 + x1 + x2;
  float q = x0 * x0 + x1 * x1 + x2 * x2;
#pragma unroll
  for (int off = 1; off < 64; off <<= 1) {
    s += __shfl_xor(s, off, 64);
    q += __shfl_xor(q, off, 64);
  }
  float m = s * (1.f / 192.f);
  float r = rsqrtf(q * (1.f / 192.f) - m * m + 1e-5f);
  __hip_bfloat16* orow = o + (size_t)tok * D_;
  orow[tid]       = __float2bfloat16((x0 - m) * r * g[tid] + bb[tid]);
  orow[tid + 64]  = __float2bfloat16((x1 - m) * r * g[tid + 64] + bb[tid + 64]);
  orow[tid + 128] = __float2bfloat16((x2 - m) * r * g[tid + 128] + bb[tid + 128]);
}

// ---------------- causal depthwise conv (DC=4) + silu -> xa ; silu(z) -> sz ----------------
__global__ __launch_bounds__(384) void k_conv(const float* __restrict__ xz,
                                              const float* __restrict__ cw_,
                                              const float* __restrict__ cb,
                                              float* __restrict__ xa,
                                              float* __restrict__ sz) {
  int row = blockIdx.x;  // b*L + l
  int l = row % L_;
  int d = threadIdx.x;
  float4 cw = *(const float4*)(cw_ + d * 4);
  const float* xc = xz + (size_t)row * 768 + d;
  float acc = cb[d];
  acc = fmaf(cw.w, xc[0], acc);
  if (l >= 1) acc = fmaf(cw.z, xc[-768], acc);
  if (l >= 2) acc = fmaf(cw.y, xc[-2 * 768], acc);
  if (l >= 3) acc = fmaf(cw.x, xc[-3 * 768], acc);
  xa[(size_t)row * DI_ + d] = acc * sigmoidf_(acc);
  float z = xc[384];
  sz[(size_t)row * DI_ + d] = z * sigmoidf_(z);
}

// ---------------- bcd = xa @ w_x^T (N=33) ; fused dt = softplus(bcd[32]*w_dt+b_dt) ----------------
__global__ __launch_bounds__(256) void k_bcd(const float* __restrict__ xa,
                                             const float* __restrict__ w_x,
                                             const float* __restrict__ w_dt,
                                             const float* __restrict__ b_dt,
                                             float* __restrict__ bcd,
                                             float* __restrict__ dt) {
  __shared__ __align__(16) float xs[4][384];
  int wv = threadIdx.x >> 6, lane = threadIdx.x & 63;
  int tok = blockIdx.x * 4 + wv;
  const float* xr = xa + (size_t)tok * DI_;
  for (int f = lane; f < 384; f += 64) xs[wv][f] = xr[f];
  float a = 0.f;
  if (lane < 33) {
    const float* wrow = w_x + lane * 384;
#pragma unroll 4
    for (int k = 0; k < 384; k += 4) {
      float4 xv = *(const float4*)(&xs[wv][k]);
      float4 ww = *(const float4*)(wrow + k);
      a = fmaf(xv.x, ww.x, a);
      a = fmaf(xv.y, ww.y, a);
      a = fmaf(xv.z, ww.z, a);
      a = fmaf(xv.w, ww.w, a);
    }
    bcd[(size_t)tok * 33 + lane] = a;
  }
  float dtraw = __shfl(a, 32, 64);
#pragma unroll
  for (int j = 0; j < 6; j++) {
    int d = lane + j * 64;
    float v = fmaf(dtraw, w_dt[d], b_dt[d]);
    dt[(size_t)tok * DI_ + d] = (v > 20.f) ? v : log1pf(expf(v));
  }
}

// ---------------- selective scan: LDS-tiled + double-buffered ----------------
// block = 256 thr = 16 d-channels x 16 n-states; serial over L in tiles of TL.
// Per tile: 5 arrays (dt, xa, sz, B, C) staged cooperatively (1 elem/thread/array,
// coalesced batched loads issued before computing the current tile). y staged in
// LDS per tile, written coalesced as bf16 by all threads.
#define TL 16
__global__ __launch_bounds__(256) void k_scan(const float* __restrict__ bcd,
                                              const float* __restrict__ dt,
                                              const float* __restrict__ xa,
                                              const float* __restrict__ sz,
                                              const float* __restrict__ A_log,
                                              const float* __restrict__ D_ssm,
                                              __hip_bfloat16* __restrict__ y) {
  __shared__ float s_in[2][5][TL][16];
  __shared__ float s_y[TL][16];
  int b = blockIdx.x / 24, chunk = blockIdx.x % 24;
  int tid = threadIdx.x;
  int dl = tid >> 4, n = tid & 15;   // compute role
  int lr = tid >> 4, lc = tid & 15;  // loader role: row-in-tile, element
  int d0 = chunk * 16;
  int d = d0 + dl;
  float Av = -expf(A_log[d * 16 + n]);
  float Dv = D_ssm[d];
  const float* dt_b = dt + (size_t)b * L_ * DI_ + d0;
  const float* xa_b = xa + (size_t)b * L_ * DI_ + d0;
  const float* sz_b = sz + (size_t)b * L_ * DI_ + d0;
  const float* bcd_b = bcd + (size_t)b * L_ * 33;
  __hip_bfloat16* y_b = y + (size_t)b * L_ * DI_ + d0;

  float v0, v1, v2, v3, v4;
#define LOAD_TILE(L0)                                      \
  {                                                        \
    int l = (L0) + lr;                                     \
    int lcl = (l < L_) ? l : (L_ - 1);                     \
    v0 = dt_b[(size_t)lcl * DI_ + lc];                     \
    v1 = xa_b[(size_t)lcl * DI_ + lc];                     \
    v2 = sz_b[(size_t)lcl * DI_ + lc];                     \
    v3 = bcd_b[lcl * 33 + lc];                             \
    v4 = bcd_b[lcl * 33 + 16 + lc];                        \
  }
#define STORE_TILE(BUF)                                    \
  {                                                        \
    s_in[BUF][0][lr][lc] = v0;                             \
    s_in[BUF][1][lr][lc] = v1;                             \
    s_in[BUF][2][lr][lc] = v2;                             \
    s_in[BUF][3][lr][lc] = v3;                             \
    s_in[BUF][4][lr][lc] = v4;                             \
  }
  LOAD_TILE(0);
  STORE_TILE(0);
  __syncthreads();
  float h = 0.f;
  const int nt = (L_ + TL - 1) / TL;  // 13
  for (int t = 0; t < nt; t++) {
    int cur = t & 1, nxt = cur ^ 1;
    if (t + 1 < nt) LOAD_TILE((t + 1) * TL);
    int lim = (t == nt - 1) ? (L_ - t * TL) : TL;
    for (int j = 0; j < lim; j++) {
      float dtv = s_in[cur][0][j][dl];
      float xv = s_in[cur][1][j][dl];
      float Bv = s_in[cur][3][j][n];
      float Cv = s_in[cur][4][j][n];
      float dA = expf(dtv * Av);
      h = fmaf(dA, h, dtv * Bv * xv);
      float c = h * Cv;
      c += __shfl_xor(c, 1, 16);
      c += __shfl_xor(c, 2, 16);
      c += __shfl_xor(c, 4, 16);
      c += __shfl_xor(c, 8, 16);
      if (n == 0) {
        float szv = s_in[cur][2][j][dl];
        s_y[j][dl] = fmaf(xv, Dv, c) * szv;
      }
    }
    __syncthreads();
    {
      int l = t * TL + lr;
      if (l < L_) y_b[(size_t)l * DI_ + lc] = __float2bfloat16(s_y[lr][lc]);
    }
    if (t + 1 < nt) STORE_TILE(nxt);
    __syncthreads();
  }
#undef LOAD_TILE
#undef STORE_TILE
}

// ---------------- final LN(token 0) + cls head + reg head ----------------
__global__ __launch_bounds__(192) void k_head(const float* __restrict__ t,
                                              const float* __restrict__ fn_g,
                                              const float* __restrict__ fn_b,
                                              const float* __restrict__ cls_w,
                                              const float* __restrict__ cls_b,
                                              const float* __restrict__ rw1,
                                              const float* __restrict__ rb1,
                                              const float* __restrict__ rw2,
                                              const float* __restrict__ rb2,
                                              float* __restrict__ out) {
  __shared__ float red[8];
  __shared__ float stats[2];
  __shared__ float feat_s[192];
  __shared__ float h_s[96];
  int b = blockIdx.x, tid = threadIdx.x;
  float x = t[(size_t)b * L_ * D_ + tid];
  float s = x, q = x * x;
#pragma unroll
  for (int off = 1; off < 64; off <<= 1) {
    s += __shfl_xor(s, off, 64);
    q += __shfl_xor(q, off, 64);
  }
  int w = tid >> 6;
  if ((tid & 63) == 0) { red[w] = s; red[4 + w] = q; }
  __syncthreads();
  if (tid == 0) {
    float ss = red[0] + red[1] + red[2];
    float qq = red[4] + red[5] + red[6];
    float m = ss * (1.f / 192.f);
    stats[0] = m;
    stats[1] = rsqrtf(qq * (1.f / 192.f) - m * m + 1e-5f);
  }
  __syncthreads();
  float fv = (x - stats[0]) * stats[1] * fn_g[tid] + fn_b[tid];
  feat_s[tid] = fv;
  __syncthreads();
  if (tid < 96) {
    float a = rb1[tid];
    const float* wr = rw1 + (size_t)tid * 192;
    for (int k = 0; k < 192; k++) a = fmaf(feat_s[k], wr[k], a);
    h_s[tid] = 0.5f * a * (1.f + erff(a * 0.70710678118654752f));
  } else if (tid < 98) {
    int c = tid - 96;
    float a = cls_b[c];
    const float* wr = cls_w + (size_t)c * 192;
    for (int k = 0; k < 192; k++) a = fmaf(feat_s[k], wr[k], a);
    out[b * 2 + c] = a;
  }
  __syncthreads();
  if (tid == 0) {
    float a = rb2[0];
    for (int j = 0; j < 96; j++) a = fmaf(h_s[j], rw2[j], a);
    out[64 + b] = a;
  }
}

extern "C" void kernel_launch(void* const* d_in, const int* in_sizes, int n_in,
                              void* d_out, int out_size, void* d_ws, size_t ws_size,
                              hipStream_t stream) {
  const float* x       = (const float*)d_in[0];
  const float* patch_w = (const float*)d_in[1];
  const float* patch_b = (const float*)d_in[2];
  const float* cls_tok = (const float*)d_in[3];
  const float* pos     = (const float*)d_in[4];
  const float* ln_g    = (const float*)d_in[5];
  const float* ln_b    = (const float*)d_in[6];
  const float* w_in    = (const float*)d_in[7];
  const float* conv_w  = (const float*)d_in[8];
  const float* conv_b  = (const float*)d_in[9];
  const float* w_x     = (const float*)d_in[10];
  const float* w_dt    = (const float*)d_in[11];
  const float* b_dt    = (const float*)d_in[12];
  const float* A_log   = (const float*)d_in[13];
  const float* D_ssm   = (const float*)d_in[14];
  const float* w_out   = (const float*)d_in[15];
  const float* fn_g    = (const float*)d_in[16];
  const float* fn_b    = (const float*)d_in[17];
  const float* cls_w   = (const float*)d_in[18];
  const float* cls_b   = (const float*)d_in[19];
  const float* reg_w1  = (const float*)d_in[20];
  const float* reg_b1  = (const float*)d_in[21];
  const float* reg_w2  = (const float*)d_in[22];
  const float* reg_b2  = (const float*)d_in[23];
  float* out = (float*)d_out;

  float* ws = (float*)d_ws;
  // workspace layout (floats); M padded to 6336 for bf16 activation buffers
  float* t_buf = ws;                        // 32*197*192 = 1,210,368
  float* xz    = t_buf + 1210368;           // 6304*768   = 4,841,472
  float* xa    = xz + 4841472;              // 6304*384   = 2,420,736
  float* szb   = xa + 2420736;              // 2,420,736
  float* bcd   = szb + 2420736;             // 6304*33    = 208,032
  float* dtb   = bcd + 208032;              // 2,420,736  (aliased by Abuf below)
  __hip_bfloat16* Abuf = (__hip_bfloat16*)dtb;  // 6272*768 bf16 (used only before layer loop)
  __hip_bfloat16* xln_bf = (__hip_bfloat16*)(dtb + 2420736);  // 6336*192 bf16 = 1,216,512
  __hip_bfloat16* y_bf   = xln_bf + 1216512;                  // 6336*384 bf16 = 2,433,024
  __hip_bfloat16* pw_bf  = y_bf + 2433024;                    // 147,456
  __hip_bfloat16* win_bf = pw_bf + 147456;                    // 589,824
  __hip_bfloat16* wout_bf = win_bf + 589824;                  // 294,912

  // weight casts (every call; same work each time)
  k_cast<<<256, 256, 0, stream>>>(patch_w, pw_bf, 147456);
  k_cast<<<256, 256, 0, stream>>>(w_in, win_bf, 589824);
  k_cast<<<256, 256, 0, stream>>>(w_out, wout_bf, 294912);

  k_cls<<<32, 192, 0, stream>>>(cls_tok, pos, t_buf);
  k_im2col<<<18816, 256, 0, stream>>>(x, Abuf);
  k_gemm_mfma<768, 2><<<dim3(98, 3), 256, 0, stream>>>(
      (const short*)Abuf, (const short*)pw_bf, t_buf, patch_b, pos, 6272);

  for (int i = 0; i < DEPTH_; i++) {
    k_ln_bf<<<B_ * L_, 64, 0, stream>>>(t_buf, ln_g + i * D_, ln_b + i * D_, xln_bf);
    k_gemm_mfma<192, 0><<<dim3(99, 12), 256, 0, stream>>>(
        (const short*)xln_bf, (const short*)(win_bf + (size_t)i * 147456), xz,
        nullptr, nullptr, 6304);
    k_conv<<<B_ * L_, 384, 0, stream>>>(xz, conv_w + i * DI_ * DC_, conv_b + i * DI_, xa, szb);
    k_bcd<<<1576, 256, 0, stream>>>(xa, w_x + i * 33 * DI_, w_dt + i * DI_, b_dt + i * DI_,
                                    bcd, dtb);
    k_scan<<<768, 256, 0, stream>>>(bcd, dtb, xa, szb, A_log + i * DI_ * DS_, D_ssm + i * DI_,
                                    y_bf);
    k_gemm_mfma<384, 1><<<dim3(99, 3), 256, 0, stream>>>(
        (const short*)y_bf, (const short*)(wout_bf + (size_t)i * 73728), t_buf,
        nullptr, nullptr, 6304);
  }
  k_head<<<32, 192, 0, stream>>>(t_buf, fn_g, fn_b, cls_w, cls_b, reg_w1, reg_b1,
                                 reg_w2, reg_b2, out);
}

// Round 5
// 712.012 us; speedup vs baseline: 1.0522x; 1.0522x over previous
//
#include <hip/hip_runtime.h>
#include <hip/hip_bf16.h>
#include <math.h>

// Problem constants
#define B_ 32
#define D_ 192
#define DEPTH_ 4
#define DI_ 384
#define DS_ 16
#define DC_ 4
#define P_ 16
#define IMG_ 224
#define N_ 196
#define L_ 197

// scan chunking
#define NCH 8
#define CHL 25   // 8*25 = 200 >= 197

typedef short s16x8 __attribute__((ext_vector_type(8)));
typedef float f32x16 __attribute__((ext_vector_type(16)));

__device__ __forceinline__ float sigmoidf_(float x) { return 1.f / (1.f + expf(-x)); }

// ---------------- weight cast fp32 -> bf16 ----------------
__global__ void k_cast(const float* __restrict__ s, __hip_bfloat16* __restrict__ d, int n) {
  for (int i = blockIdx.x * 256 + threadIdx.x; i < n; i += gridDim.x * 256)
    d[i] = __float2bfloat16(s[i]);
}

// ---------------- cls token + pos embed (row l=0) ----------------
__global__ void k_cls(const float* __restrict__ cls_tok, const float* __restrict__ pos,
                      float* __restrict__ t) {
  int b = blockIdx.x, d = threadIdx.x;
  t[(size_t)b * L_ * D_ + d] = cls_tok[d] + pos[d];
}

// ---------------- im2col: x (B,3,224,224) -> A bf16 (6272 x 768) ----------------
__global__ __launch_bounds__(256) void k_im2col(const float* __restrict__ x,
                                                __hip_bfloat16* __restrict__ A) {
  int idx = blockIdx.x * 256 + threadIdx.x;  // grid exact: 18816*256 = 6272*768
  int tok = idx / 768, f = idx - tok * 768;
  int b = tok / 196, p = tok - b * 196;
  int h = p / 14, w = p - h * 14;
  int c = f >> 8, i = (f >> 4) & 15, j = f & 15;
  float v = x[(((size_t)(b * 3 + c) * 224 + h * 16 + i) * 224 + w * 16 + j)];
  A[idx] = __float2bfloat16(v);
}

// ---------------- generic bf16 MFMA GEMM: C[M x N] = A[M x K] @ W[N x K]^T ----------------
// block = 256 thr (4 waves), tile M64 x N64, wave tile 32x32 (mfma_f32_32x32x16_bf16)
// K-chunks of 96 staged in LDS (both operands), stride 104 to tame bank conflicts.
// MODE 0: C (stride 768) = acc                       (xz = ln(t) @ w_in^T)
// MODE 1: C (stride 192) += acc                      (t += y @ w_out^T)
// MODE 2: patch epilogue: t[(b*197+1+p)*192+n] = acc + bias[n] + pos[(1+p)*192+n]
template <int KTOT, int MODE>
__global__ __launch_bounds__(256) void k_gemm_mfma(const short* __restrict__ A,
                                                   const short* __restrict__ Wb,
                                                   float* __restrict__ C,
                                                   const float* __restrict__ bias,
                                                   const float* __restrict__ pos,
                                                   int M) {
  constexpr int KC = 96;
  constexpr int STR = 104;  // 208 B row stride -> 4-way bank conflict worst case (1.58x)
  __shared__ __align__(16) short Als[64 * STR];
  __shared__ __align__(16) short Bls[64 * STR];
  int m0 = blockIdx.x * 64, n0 = blockIdx.y * 64;
  int tid = threadIdx.x;
  int lane = tid & 63, wid = tid >> 6;
  int mw = (wid & 1) * 32, nw = (wid >> 1) * 32;
  int l31 = lane & 31, lh = lane >> 5;
  f32x16 acc;
#pragma unroll
  for (int i = 0; i < 16; i++) acc[i] = 0.f;
  for (int kc = 0; kc < KTOT; kc += KC) {
    __syncthreads();
#pragma unroll
    for (int i = 0; i < 3; i++) {
      int seg = tid + i * 256;        // 768 segments: 64 rows x 12 k-segs of 8 bf16
      int r = seg / 12, s = seg - r * 12;
      *(s16x8*)(Als + r * STR + s * 8) =
          *(const s16x8*)(A + (size_t)(m0 + r) * KTOT + kc + s * 8);
      *(s16x8*)(Bls + r * STR + s * 8) =
          *(const s16x8*)(Wb + (size_t)(n0 + r) * KTOT + kc + s * 8);
    }
    __syncthreads();
#pragma unroll
    for (int ks = 0; ks < KC / 16; ks++) {
      s16x8 af = *(const s16x8*)(Als + (mw + l31) * STR + ks * 16 + lh * 8);
      s16x8 bf = *(const s16x8*)(Bls + (nw + l31) * STR + ks * 16 + lh * 8);
      acc = __builtin_amdgcn_mfma_f32_32x32x16_bf16(af, bf, acc, 0, 0, 0);
    }
  }
  // epilogue: C/D layout col=lane&31, row=(reg&3)+8*(reg>>2)+4*(lane>>5)
  int gn = n0 + nw + l31;
#pragma unroll
  for (int i = 0; i < 16; i++) {
    int rowt = mw + (i & 3) + 8 * (i >> 2) + 4 * lh;
    int gm = m0 + rowt;
    float v = acc[i];
    if (MODE == 0) {
      if (gm < M) C[(size_t)gm * 768 + gn] = v;
    } else if (MODE == 1) {
      if (gm < M) C[(size_t)gm * 192 + gn] += v;
    } else {
      int b = gm / 196, p = gm - b * 196;
      C[((size_t)b * 197 + 1 + p) * 192 + gn] =
          v + bias[gn] + pos[(size_t)(1 + p) * 192 + gn];
    }
  }
}

// ---------------- LayerNorm per token -> bf16 out ----------------
__global__ __launch_bounds__(64) void k_ln_bf(const float* __restrict__ t,
                                              const float* __restrict__ g,
                                              const float* __restrict__ bb,
                                              __hip_bfloat16* __restrict__ o) {
  int tok = blockIdx.x, tid = threadIdx.x;
  const float* xr = t + (size_t)tok * D_;
  float x0 = xr[tid], x1 = xr[tid + 64], x2 = xr[tid + 128];
  float s = x0 + x1 + x2;
  float q = x0 * x0 + x1 * x1 + x2 * x2;
#pragma unroll
  for (int off = 1; off < 64; off <<= 1) {
    s += __shfl_xor(s, off, 64);
    q += __shfl_xor(q, off, 64);
  }
  float m = s * (1.f / 192.f);
  float r = rsqrtf(q * (1.f / 192.f) - m * m + 1e-5f);
  __hip_bfloat16* orow = o + (size_t)tok * D_;
  orow[tid]       = __float2bfloat16((x0 - m) * r * g[tid] + bb[tid]);
  orow[tid + 64]  = __float2bfloat16((x1 - m) * r * g[tid + 64] + bb[tid + 64]);
  orow[tid + 128] = __float2bfloat16((x2 - m) * r * g[tid + 128] + bb[tid + 128]);
}

// ---------------- causal depthwise conv (DC=4) + silu -> xa ; silu(z) -> sz ----------------
__global__ __launch_bounds__(384) void k_conv(const float* __restrict__ xz,
                                              const float* __restrict__ cw_,
                                              const float* __restrict__ cb,
                                              float* __restrict__ xa,
                                              float* __restrict__ sz) {
  int row = blockIdx.x;  // b*L + l
  int l = row % L_;
  int d = threadIdx.x;
  float4 cw = *(const float4*)(cw_ + d * 4);
  const float* xc = xz + (size_t)row * 768 + d;
  float acc = cb[d];
  acc = fmaf(cw.w, xc[0], acc);
  if (l >= 1) acc = fmaf(cw.z, xc[-768], acc);
  if (l >= 2) acc = fmaf(cw.y, xc[-2 * 768], acc);
  if (l >= 3) acc = fmaf(cw.x, xc[-3 * 768], acc);
  xa[(size_t)row * DI_ + d] = acc * sigmoidf_(acc);
  float z = xc[384];
  sz[(size_t)row * DI_ + d] = z * sigmoidf_(z);
}

// ---------------- bcd = xa @ w_x^T (N=33) ; fused dt = softplus(bcd[32]*w_dt+b_dt) ----------------
__global__ __launch_bounds__(256) void k_bcd(const float* __restrict__ xa,
                                             const float* __restrict__ w_x,
                                             const float* __restrict__ w_dt,
                                             const float* __restrict__ b_dt,
                                             float* __restrict__ bcd,
                                             float* __restrict__ dt) {
  __shared__ __align__(16) float xs[4][384];
  int wv = threadIdx.x >> 6, lane = threadIdx.x & 63;
  int tok = blockIdx.x * 4 + wv;
  const float* xr = xa + (size_t)tok * DI_;
  for (int f = lane; f < 384; f += 64) xs[wv][f] = xr[f];
  float a = 0.f;
  if (lane < 33) {
    const float* wrow = w_x + lane * 384;
#pragma unroll 4
    for (int k = 0; k < 384; k += 4) {
      float4 xv = *(const float4*)(&xs[wv][k]);
      float4 ww = *(const float4*)(wrow + k);
      a = fmaf(xv.x, ww.x, a);
      a = fmaf(xv.y, ww.y, a);
      a = fmaf(xv.z, ww.z, a);
      a = fmaf(xv.w, ww.w, a);
    }
    bcd[(size_t)tok * 33 + lane] = a;
  }
  float dtraw = __shfl(a, 32, 64);
#pragma unroll
  for (int j = 0; j < 6; j++) {
    int d = lane + j * 64;
    float v = fmaf(dtraw, w_dt[d], b_dt[d]);
    dt[(size_t)tok * DI_ + d] = (v > 20.f) ? v : log1pf(expf(v));
  }
}

// ---------------- selective scan, 3-phase chunked parallel scan ----------------
// Phase 1: per (b,chunk): chunk-local scan with h=0; lanes=d, h[16]+P[16] in VGPRs.
// Stores P (prod of dA) and h_local at chunk end, layout [b][ch][d][n].
__global__ __launch_bounds__(384) void k_scan1(const float* __restrict__ dt,
                                               const float* __restrict__ xa,
                                               const float* __restrict__ bcd,
                                               const float* __restrict__ A_log,
                                               float* __restrict__ Pst,
                                               float* __restrict__ Hst) {
  int b = blockIdx.x >> 3, ch = blockIdx.x & 7;
  int d = threadIdx.x;
  int l0 = ch * CHL;
  int lim = min(CHL, L_ - l0);
  float Av[16];
#pragma unroll
  for (int n = 0; n < 16; n++) Av[n] = -expf(A_log[d * 16 + n]);
  const float* dtp = dt + ((size_t)b * L_ + l0) * DI_ + d;
  const float* xap = xa + ((size_t)b * L_ + l0) * DI_ + d;
  const float* bp = bcd + ((size_t)b * L_ + l0) * 33;
  float h[16], Pp[16];
#pragma unroll
  for (int n = 0; n < 16; n++) { h[n] = 0.f; Pp[n] = 1.f; }
  float dtv = dtp[0], xv = xap[0];
  for (int j = 0; j < lim; j++) {
    int jn = (j + 1 < lim) ? (j + 1) : j;
    float dtn = dtp[(size_t)jn * DI_];
    float xn = xap[(size_t)jn * DI_];
    float Bn[16];
#pragma unroll
    for (int n = 0; n < 16; n++) Bn[n] = bp[j * 33 + n];   // wave-uniform -> scalarized
    float dtx = dtv * xv;
#pragma unroll
    for (int n = 0; n < 16; n++) {
      float dA = __expf(dtv * Av[n]);
      h[n] = fmaf(dA, h[n], dtx * Bn[n]);
      Pp[n] *= dA;
    }
    dtv = dtn; xv = xn;
  }
  size_t s = ((size_t)blockIdx.x * 384 + d) * 16;
#pragma unroll
  for (int q = 0; q < 4; q++) {
    *(float4*)(Pst + s + q * 4) = make_float4(Pp[q * 4], Pp[q * 4 + 1], Pp[q * 4 + 2], Pp[q * 4 + 3]);
    *(float4*)(Hst + s + q * 4) = make_float4(h[q * 4], h[q * 4 + 1], h[q * 4 + 2], h[q * 4 + 3]);
  }
}

// Phase 2: cross-chunk propagation: hinit[b][0]=0; hinit[b][c]=P[c-1]*hinit[c-1]+Hloc[c-1]
__global__ __launch_bounds__(256) void k_scan_mid(const float* __restrict__ Pst,
                                                  const float* __restrict__ Hst,
                                                  float* __restrict__ Hinit) {
  int idx = blockIdx.x * 256 + threadIdx.x;  // 32*6144 = 196608
  int b = idx / 6144, r = idx - b * 6144;
  float h = 0.f;
#pragma unroll
  for (int c = 0; c < NCH; c++) {
    size_t o = (size_t)(b * NCH + c) * 6144 + r;
    Hinit[o] = h;
    h = fmaf(Pst[o], h, Hst[o]);
  }
}

// Phase 3: rescan each chunk seeded with hinit; fused C-dot, D-term, silu(z); y -> bf16
__global__ __launch_bounds__(384) void k_scan2(const float* __restrict__ dt,
                                               const float* __restrict__ xa,
                                               const float* __restrict__ sz,
                                               const float* __restrict__ bcd,
                                               const float* __restrict__ A_log,
                                               const float* __restrict__ D_ssm,
                                               const float* __restrict__ Hinit,
                                               __hip_bfloat16* __restrict__ y) {
  int b = blockIdx.x >> 3, ch = blockIdx.x & 7;
  int d = threadIdx.x;
  int l0 = ch * CHL;
  int lim = min(CHL, L_ - l0);
  float Av[16];
#pragma unroll
  for (int n = 0; n < 16; n++) Av[n] = -expf(A_log[d * 16 + n]);
  float Dv = D_ssm[d];
  const float* dtp = dt + ((size_t)b * L_ + l0) * DI_ + d;
  const float* xap = xa + ((size_t)b * L_ + l0) * DI_ + d;
  const float* szp = sz + ((size_t)b * L_ + l0) * DI_ + d;
  const float* bp = bcd + ((size_t)b * L_ + l0) * 33;
  __hip_bfloat16* yp = y + ((size_t)b * L_ + l0) * DI_ + d;
  float h[16];
  {
    size_t s = ((size_t)blockIdx.x * 384 + d) * 16;
#pragma unroll
    for (int q = 0; q < 4; q++) {
      float4 v = *(const float4*)(Hinit + s + q * 4);
      h[q * 4] = v.x; h[q * 4 + 1] = v.y; h[q * 4 + 2] = v.z; h[q * 4 + 3] = v.w;
    }
  }
  float dtv = dtp[0], xv = xap[0], szv = szp[0];
  for (int j = 0; j < lim; j++) {
    int jn = (j + 1 < lim) ? (j + 1) : j;
    float dtn = dtp[(size_t)jn * DI_];
    float xn = xap[(size_t)jn * DI_];
    float szn = szp[(size_t)jn * DI_];
    float Bn[16], Cn[16];
#pragma unroll
    for (int n = 0; n < 16; n++) Bn[n] = bp[j * 33 + n];        // wave-uniform
#pragma unroll
    for (int n = 0; n < 16; n++) Cn[n] = bp[j * 33 + 16 + n];   // wave-uniform
    float dtx = dtv * xv;
    float acc = 0.f;
#pragma unroll
    for (int n = 0; n < 16; n++) {
      float dA = __expf(dtv * Av[n]);
      h[n] = fmaf(dA, h[n], dtx * Bn[n]);
      acc = fmaf(h[n], Cn[n], acc);
    }
    float yv = fmaf(xv, Dv, acc) * szv;
    yp[(size_t)j * DI_] = __float2bfloat16(yv);
    dtv = dtn; xv = xn; szv = szn;
  }
}

// ---------------- final LN(token 0) + cls head + reg head ----------------
__global__ __launch_bounds__(192) void k_head(const float* __restrict__ t,
                                              const float* __restrict__ fn_g,
                                              const float* __restrict__ fn_b,
                                              const float* __restrict__ cls_w,
                                              const float* __restrict__ cls_b,
                                              const float* __restrict__ rw1,
                                              const float* __restrict__ rb1,
                                              const float* __restrict__ rw2,
                                              const float* __restrict__ rb2,
                                              float* __restrict__ out) {
  __shared__ float red[8];
  __shared__ float stats[2];
  __shared__ float feat_s[192];
  __shared__ float h_s[96];
  int b = blockIdx.x, tid = threadIdx.x;
  float x = t[(size_t)b * L_ * D_ + tid];
  float s = x, q = x * x;
#pragma unroll
  for (int off = 1; off < 64; off <<= 1) {
    s += __shfl_xor(s, off, 64);
    q += __shfl_xor(q, off, 64);
  }
  int w = tid >> 6;
  if ((tid & 63) == 0) { red[w] = s; red[4 + w] = q; }
  __syncthreads();
  if (tid == 0) {
    float ss = red[0] + red[1] + red[2];
    float qq = red[4] + red[5] + red[6];
    float m = ss * (1.f / 192.f);
    stats[0] = m;
    stats[1] = rsqrtf(qq * (1.f / 192.f) - m * m + 1e-5f);
  }
  __syncthreads();
  float fv = (x - stats[0]) * stats[1] * fn_g[tid] + fn_b[tid];
  feat_s[tid] = fv;
  __syncthreads();
  if (tid < 96) {
    float a = rb1[tid];
    const float* wr = rw1 + (size_t)tid * 192;
    for (int k = 0; k < 192; k++) a = fmaf(feat_s[k], wr[k], a);
    h_s[tid] = 0.5f * a * (1.f + erff(a * 0.70710678118654752f));
  } else if (tid < 98) {
    int c = tid - 96;
    float a = cls_b[c];
    const float* wr = cls_w + (size_t)c * 192;
    for (int k = 0; k < 192; k++) a = fmaf(feat_s[k], wr[k], a);
    out[b * 2 + c] = a;
  }
  __syncthreads();
  if (tid == 0) {
    float a = rb2[0];
    for (int j = 0; j < 96; j++) a = fmaf(h_s[j], rw2[j], a);
    out[64 + b] = a;
  }
}

extern "C" void kernel_launch(void* const* d_in, const int* in_sizes, int n_in,
                              void* d_out, int out_size, void* d_ws, size_t ws_size,
                              hipStream_t stream) {
  const float* x       = (const float*)d_in[0];
  const float* patch_w = (const float*)d_in[1];
  const float* patch_b = (const float*)d_in[2];
  const float* cls_tok = (const float*)d_in[3];
  const float* pos     = (const float*)d_in[4];
  const float* ln_g    = (const float*)d_in[5];
  const float* ln_b    = (const float*)d_in[6];
  const float* w_in    = (const float*)d_in[7];
  const float* conv_w  = (const float*)d_in[8];
  const float* conv_b  = (const float*)d_in[9];
  const float* w_x     = (const float*)d_in[10];
  const float* w_dt    = (const float*)d_in[11];
  const float* b_dt    = (const float*)d_in[12];
  const float* A_log   = (const float*)d_in[13];
  const float* D_ssm   = (const float*)d_in[14];
  const float* w_out   = (const float*)d_in[15];
  const float* fn_g    = (const float*)d_in[16];
  const float* fn_b    = (const float*)d_in[17];
  const float* cls_w   = (const float*)d_in[18];
  const float* cls_b   = (const float*)d_in[19];
  const float* reg_w1  = (const float*)d_in[20];
  const float* reg_b1  = (const float*)d_in[21];
  const float* reg_w2  = (const float*)d_in[22];
  const float* reg_b2  = (const float*)d_in[23];
  float* out = (float*)d_out;

  float* ws = (float*)d_ws;
  // workspace layout (floats); M padded to 6336 for bf16 activation buffers
  float* t_buf = ws;                        // 32*197*192 = 1,210,368
  float* xz    = t_buf + 1210368;           // 6304*768   = 4,841,472
  float* xa    = xz + 4841472;              // 6304*384   = 2,420,736
  float* szb   = xa + 2420736;              // 2,420,736
  float* bcd   = szb + 2420736;             // 6304*33    = 208,032
  float* dtb   = bcd + 208032;              // 2,420,736  (aliased by Abuf below)
  __hip_bfloat16* Abuf = (__hip_bfloat16*)dtb;  // 6272*768 bf16 (used only before layer loop)
  __hip_bfloat16* xln_bf = (__hip_bfloat16*)(dtb + 2420736);  // 6336*192 bf16 = 1,216,512
  __hip_bfloat16* y_bf   = xln_bf + 1216512;                  // 6336*384 bf16 = 2,433,024
  __hip_bfloat16* pw_bf  = y_bf + 2433024;                    // 147,456
  __hip_bfloat16* win_bf = pw_bf + 147456;                    // 589,824
  __hip_bfloat16* wout_bf = win_bf + 589824;                  // 294,912
  float* Pst   = (float*)(wout_bf + 294912);  // 32*8*384*16 = 1,572,864 floats
  float* Hst   = Pst + 1572864;               // 1,572,864
  float* Hinit = Hst + 1572864;               // 1,572,864

  // weight casts (every call; same work each time)
  k_cast<<<256, 256, 0, stream>>>(patch_w, pw_bf, 147456);
  k_cast<<<256, 256, 0, stream>>>(w_in, win_bf, 589824);
  k_cast<<<256, 256, 0, stream>>>(w_out, wout_bf, 294912);

  k_cls<<<32, 192, 0, stream>>>(cls_tok, pos, t_buf);
  k_im2col<<<18816, 256, 0, stream>>>(x, Abuf);
  k_gemm_mfma<768, 2><<<dim3(98, 3), 256, 0, stream>>>(
      (const short*)Abuf, (const short*)pw_bf, t_buf, patch_b, pos, 6272);

  for (int i = 0; i < DEPTH_; i++) {
    k_ln_bf<<<B_ * L_, 64, 0, stream>>>(t_buf, ln_g + i * D_, ln_b + i * D_, xln_bf);
    k_gemm_mfma<192, 0><<<dim3(99, 12), 256, 0, stream>>>(
        (const short*)xln_bf, (const short*)(win_bf + (size_t)i * 147456), xz,
        nullptr, nullptr, 6304);
    k_conv<<<B_ * L_, 384, 0, stream>>>(xz, conv_w + i * DI_ * DC_, conv_b + i * DI_, xa, szb);
    k_bcd<<<1576, 256, 0, stream>>>(xa, w_x + i * 33 * DI_, w_dt + i * DI_, b_dt + i * DI_,
                                    bcd, dtb);
    k_scan1<<<B_ * NCH, 384, 0, stream>>>(dtb, xa, bcd, A_log + i * DI_ * DS_, Pst, Hst);
    k_scan_mid<<<768, 256, 0, stream>>>(Pst, Hst, Hinit);
    k_scan2<<<B_ * NCH, 384, 0, stream>>>(dtb, xa, szb, bcd, A_log + i * DI_ * DS_,
                                          D_ssm + i * DI_, Hinit, y_bf);
    k_gemm_mfma<384, 1><<<dim3(99, 3), 256, 0, stream>>>(
        (const short*)y_bf, (const short*)(wout_bf + (size_t)i * 73728), t_buf,
        nullptr, nullptr, 6304);
  }
  k_head<<<32, 192, 0, stream>>>(t_buf, fn_g, fn_b, cls_w, cls_b, reg_w1, reg_b1,
                                 reg_w2, reg_b2, out);
}

// Round 6
// 528.944 us; speedup vs baseline: 1.4163x; 1.3461x over previous
//
#include <hip/hip_runtime.h>
#include <hip/hip_bf16.h>
#include <math.h>

// Problem constants
#define B_ 32
#define D_ 192
#define DEPTH_ 4
#define DI_ 384
#define DS_ 16
#define DC_ 4
#define P_ 16
#define IMG_ 224
#define N_ 196
#define L_ 197

// scan chunking
#define NCH 8
#define CHL 25   // 8*25 = 200 >= 197

typedef short s16x8 __attribute__((ext_vector_type(8)));
typedef float f32x16 __attribute__((ext_vector_type(16)));

__device__ __forceinline__ float sigmoidf_(float x) { return 1.f / (1.f + expf(-x)); }

// ---------------- weight cast fp32 -> bf16 ----------------
__global__ void k_cast(const float* __restrict__ s, __hip_bfloat16* __restrict__ d, int n) {
  for (int i = blockIdx.x * 256 + threadIdx.x; i < n; i += gridDim.x * 256)
    d[i] = __float2bfloat16(s[i]);
}

// ---------------- w_x cast: (DEPTH,33,384) -> (DEPTH,64,384) bf16 zero-padded ----------------
__global__ void k_cast_wx(const float* __restrict__ s, __hip_bfloat16* __restrict__ d) {
  int i = blockIdx.x * 256 + threadIdx.x;  // 384 blocks: 4*64*384 = 98304 exact
  int li = i / 24576;
  int r = (i / 384) & 63;
  int c = i % 384;
  d[i] = (r < 33) ? __float2bfloat16(s[(li * 33 + r) * 384 + c]) : __float2bfloat16(0.f);
}

// ---------------- cls token + pos embed (row l=0) ----------------
__global__ void k_cls(const float* __restrict__ cls_tok, const float* __restrict__ pos,
                      float* __restrict__ t) {
  int b = blockIdx.x, d = threadIdx.x;
  t[(size_t)b * L_ * D_ + d] = cls_tok[d] + pos[d];
}

// ---------------- im2col: x (B,3,224,224) -> A bf16 (6272 x 768) ----------------
__global__ __launch_bounds__(256) void k_im2col(const float* __restrict__ x,
                                                __hip_bfloat16* __restrict__ A) {
  int idx = blockIdx.x * 256 + threadIdx.x;  // grid exact: 18816*256 = 6272*768
  int tok = idx / 768, f = idx - tok * 768;
  int b = tok / 196, p = tok - b * 196;
  int h = p / 14, w = p - h * 14;
  int c = f >> 8, i = (f >> 4) & 15, j = f & 15;
  float v = x[(((size_t)(b * 3 + c) * 224 + h * 16 + i) * 224 + w * 16 + j)];
  A[idx] = __float2bfloat16(v);
}

// ---------------- generic bf16 MFMA GEMM: C[M x N] = A[M x K] @ W[N x K]^T ----------------
// block = 256 thr (4 waves), tile M64 x N64, wave tile 32x32 (mfma_f32_32x32x16_bf16)
// K-chunks of 96 staged in LDS (both operands), stride 104 to tame bank conflicts.
// MODE 0: C (stride 768) = acc                       (xz = ln(t) @ w_in^T)
// MODE 1: C (stride 192) += acc                      (t += y @ w_out^T)
// MODE 2: patch epilogue: t[(b*197+1+p)*192+n] = acc + bias[n] + pos[(1+p)*192+n]
// MODE 3: C (stride 64)  = acc                       (bcd = xa @ w_x_pad^T)
template <int KTOT, int MODE>
__global__ __launch_bounds__(256) void k_gemm_mfma(const short* __restrict__ A,
                                                   const short* __restrict__ Wb,
                                                   float* __restrict__ C,
                                                   const float* __restrict__ bias,
                                                   const float* __restrict__ pos,
                                                   int M) {
  constexpr int KC = 96;
  constexpr int STR = 104;  // 208 B row stride -> 4-way bank conflict worst case (1.58x)
  __shared__ __align__(16) short Als[64 * STR];
  __shared__ __align__(16) short Bls[64 * STR];
  int m0 = blockIdx.x * 64, n0 = blockIdx.y * 64;
  int tid = threadIdx.x;
  int lane = tid & 63, wid = tid >> 6;
  int mw = (wid & 1) * 32, nw = (wid >> 1) * 32;
  int l31 = lane & 31, lh = lane >> 5;
  f32x16 acc;
#pragma unroll
  for (int i = 0; i < 16; i++) acc[i] = 0.f;
  for (int kc = 0; kc < KTOT; kc += KC) {
    __syncthreads();
#pragma unroll
    for (int i = 0; i < 3; i++) {
      int seg = tid + i * 256;        // 768 segments: 64 rows x 12 k-segs of 8 bf16
      int r = seg / 12, s = seg - r * 12;
      *(s16x8*)(Als + r * STR + s * 8) =
          *(const s16x8*)(A + (size_t)(m0 + r) * KTOT + kc + s * 8);
      *(s16x8*)(Bls + r * STR + s * 8) =
          *(const s16x8*)(Wb + (size_t)(n0 + r) * KTOT + kc + s * 8);
    }
    __syncthreads();
#pragma unroll
    for (int ks = 0; ks < KC / 16; ks++) {
      s16x8 af = *(const s16x8*)(Als + (mw + l31) * STR + ks * 16 + lh * 8);
      s16x8 bf = *(const s16x8*)(Bls + (nw + l31) * STR + ks * 16 + lh * 8);
      acc = __builtin_amdgcn_mfma_f32_32x32x16_bf16(af, bf, acc, 0, 0, 0);
    }
  }
  // epilogue: C/D layout col=lane&31, row=(reg&3)+8*(reg>>2)+4*(lane>>5)
  int gn = n0 + nw + l31;
#pragma unroll
  for (int i = 0; i < 16; i++) {
    int rowt = mw + (i & 3) + 8 * (i >> 2) + 4 * lh;
    int gm = m0 + rowt;
    float v = acc[i];
    if (MODE == 0) {
      if (gm < M) C[(size_t)gm * 768 + gn] = v;
    } else if (MODE == 1) {
      if (gm < M) C[(size_t)gm * 192 + gn] += v;
    } else if (MODE == 3) {
      if (gm < M) C[(size_t)gm * 64 + gn] = v;
    } else {
      int b = gm / 196, p = gm - b * 196;
      C[((size_t)b * 197 + 1 + p) * 192 + gn] =
          v + bias[gn] + pos[(size_t)(1 + p) * 192 + gn];
    }
  }
}

// ---------------- LayerNorm per token -> bf16 out ----------------
__global__ __launch_bounds__(64) void k_ln_bf(const float* __restrict__ t,
                                              const float* __restrict__ g,
                                              const float* __restrict__ bb,
                                              __hip_bfloat16* __restrict__ o) {
  int tok = blockIdx.x, tid = threadIdx.x;
  const float* xr = t + (size_t)tok * D_;
  float x0 = xr[tid], x1 = xr[tid + 64], x2 = xr[tid + 128];
  float s = x0 + x1 + x2;
  float q = x0 * x0 + x1 * x1 + x2 * x2;
#pragma unroll
  for (int off = 1; off < 64; off <<= 1) {
    s += __shfl_xor(s, off, 64);
    q += __shfl_xor(q, off, 64);
  }
  float m = s * (1.f / 192.f);
  float r = rsqrtf(q * (1.f / 192.f) - m * m + 1e-5f);
  __hip_bfloat16* orow = o + (size_t)tok * D_;
  orow[tid]       = __float2bfloat16((x0 - m) * r * g[tid] + bb[tid]);
  orow[tid + 64]  = __float2bfloat16((x1 - m) * r * g[tid + 64] + bb[tid + 64]);
  orow[tid + 128] = __float2bfloat16((x2 - m) * r * g[tid + 128] + bb[tid + 128]);
}

// ---------------- causal depthwise conv (DC=4) + silu -> xa (fp32 + bf16) ; silu(z) -> sz ----------------
__global__ __launch_bounds__(384) void k_conv(const float* __restrict__ xz,
                                              const float* __restrict__ cw_,
                                              const float* __restrict__ cb,
                                              float* __restrict__ xa,
                                              __hip_bfloat16* __restrict__ xa_bf,
                                              float* __restrict__ sz) {
  int row = blockIdx.x;  // b*L + l
  int l = row % L_;
  int d = threadIdx.x;
  float4 cw = *(const float4*)(cw_ + d * 4);
  const float* xc = xz + (size_t)row * 768 + d;
  float acc = cb[d];
  acc = fmaf(cw.w, xc[0], acc);
  if (l >= 1) acc = fmaf(cw.z, xc[-768], acc);
  if (l >= 2) acc = fmaf(cw.y, xc[-2 * 768], acc);
  if (l >= 3) acc = fmaf(cw.x, xc[-3 * 768], acc);
  float xav = acc * sigmoidf_(acc);
  xa[(size_t)row * DI_ + d] = xav;
  xa_bf[(size_t)row * DI_ + d] = __float2bfloat16(xav);
  float z = xc[384];
  sz[(size_t)row * DI_ + d] = z * sigmoidf_(z);
}

// ---------------- selective scan, 3-phase chunked parallel scan ----------------
// dt = softplus(bcd[:,32]*w_dt[d]+b_dt[d]) computed inline (no dt buffer).
// bcd layout: [tok][64]: cols 0..15 = B, 16..31 = C, 32 = dt raw.
// Phase 1: per (b,chunk): chunk-local scan with h=0; lanes=d, h[16]+P[16] in VGPRs.
__global__ __launch_bounds__(384) void k_scan1(const float* __restrict__ xa,
                                               const float* __restrict__ bcd,
                                               const float* __restrict__ A_log,
                                               const float* __restrict__ w_dt,
                                               const float* __restrict__ b_dt,
                                               float* __restrict__ Pst,
                                               float* __restrict__ Hst) {
  int b = blockIdx.x >> 3, ch = blockIdx.x & 7;
  int d = threadIdx.x;
  int l0 = ch * CHL;
  int lim = min(CHL, L_ - l0);
  float Av[16];
#pragma unroll
  for (int n = 0; n < 16; n++) Av[n] = -expf(A_log[d * 16 + n]);
  float wdt = w_dt[d], bdt = b_dt[d];
  const float* xap = xa + ((size_t)b * L_ + l0) * DI_ + d;
  const float* bp = bcd + ((size_t)b * L_ + l0) * 64;
  float h[16], Pp[16];
#pragma unroll
  for (int n = 0; n < 16; n++) { h[n] = 0.f; Pp[n] = 1.f; }
  float xv = xap[0];
  for (int j = 0; j < lim; j++) {
    int jn = (j + 1 < lim) ? (j + 1) : j;
    float xn = xap[(size_t)jn * DI_];
    float dtraw = bp[j * 64 + 32];           // wave-uniform -> scalarized
    float Bn[16];
#pragma unroll
    for (int n = 0; n < 16; n++) Bn[n] = bp[j * 64 + n];   // wave-uniform
    float v = fmaf(dtraw, wdt, bdt);
    float dtv = (v > 20.f) ? v : __logf(1.f + __expf(v));
    float dtx = dtv * xv;
#pragma unroll
    for (int n = 0; n < 16; n++) {
      float dA = __expf(dtv * Av[n]);
      h[n] = fmaf(dA, h[n], dtx * Bn[n]);
      Pp[n] *= dA;
    }
    xv = xn;
  }
  size_t s = ((size_t)blockIdx.x * 384 + d) * 16;
#pragma unroll
  for (int q = 0; q < 4; q++) {
    *(float4*)(Pst + s + q * 4) = make_float4(Pp[q * 4], Pp[q * 4 + 1], Pp[q * 4 + 2], Pp[q * 4 + 3]);
    *(float4*)(Hst + s + q * 4) = make_float4(h[q * 4], h[q * 4 + 1], h[q * 4 + 2], h[q * 4 + 3]);
  }
}

// Phase 2: cross-chunk propagation: hinit[b][0]=0; hinit[b][c]=P[c-1]*hinit[c-1]+Hloc[c-1]
__global__ __launch_bounds__(256) void k_scan_mid(const float* __restrict__ Pst,
                                                  const float* __restrict__ Hst,
                                                  float* __restrict__ Hinit) {
  int idx = blockIdx.x * 256 + threadIdx.x;  // 32*6144 = 196608
  int b = idx / 6144, r = idx - b * 6144;
  float h = 0.f;
#pragma unroll
  for (int c = 0; c < NCH; c++) {
    size_t o = (size_t)(b * NCH + c) * 6144 + r;
    Hinit[o] = h;
    h = fmaf(Pst[o], h, Hst[o]);
  }
}

// Phase 3: rescan each chunk seeded with hinit; fused C-dot, D-term, silu(z); y -> bf16
__global__ __launch_bounds__(384) void k_scan2(const float* __restrict__ xa,
                                               const float* __restrict__ sz,
                                               const float* __restrict__ bcd,
                                               const float* __restrict__ A_log,
                                               const float* __restrict__ D_ssm,
                                               const float* __restrict__ w_dt,
                                               const float* __restrict__ b_dt,
                                               const float* __restrict__ Hinit,
                                               __hip_bfloat16* __restrict__ y) {
  int b = blockIdx.x >> 3, ch = blockIdx.x & 7;
  int d = threadIdx.x;
  int l0 = ch * CHL;
  int lim = min(CHL, L_ - l0);
  float Av[16];
#pragma unroll
  for (int n = 0; n < 16; n++) Av[n] = -expf(A_log[d * 16 + n]);
  float Dv = D_ssm[d];
  float wdt = w_dt[d], bdt = b_dt[d];
  const float* xap = xa + ((size_t)b * L_ + l0) * DI_ + d;
  const float* szp = sz + ((size_t)b * L_ + l0) * DI_ + d;
  const float* bp = bcd + ((size_t)b * L_ + l0) * 64;
  __hip_bfloat16* yp = y + ((size_t)b * L_ + l0) * DI_ + d;
  float h[16];
  {
    size_t s = ((size_t)blockIdx.x * 384 + d) * 16;
#pragma unroll
    for (int q = 0; q < 4; q++) {
      float4 v = *(const float4*)(Hinit + s + q * 4);
      h[q * 4] = v.x; h[q * 4 + 1] = v.y; h[q * 4 + 2] = v.z; h[q * 4 + 3] = v.w;
    }
  }
  float xv = xap[0], szv = szp[0];
  for (int j = 0; j < lim; j++) {
    int jn = (j + 1 < lim) ? (j + 1) : j;
    float xn = xap[(size_t)jn * DI_];
    float szn = szp[(size_t)jn * DI_];
    float dtraw = bp[j * 64 + 32];
    float Bn[16], Cn[16];
#pragma unroll
    for (int n = 0; n < 16; n++) Bn[n] = bp[j * 64 + n];        // wave-uniform
#pragma unroll
    for (int n = 0; n < 16; n++) Cn[n] = bp[j * 64 + 16 + n];   // wave-uniform
    float v = fmaf(dtraw, wdt, bdt);
    float dtv = (v > 20.f) ? v : __logf(1.f + __expf(v));
    float dtx = dtv * xv;
    float acc = 0.f;
#pragma unroll
    for (int n = 0; n < 16; n++) {
      float dA = __expf(dtv * Av[n]);
      h[n] = fmaf(dA, h[n], dtx * Bn[n]);
      acc = fmaf(h[n], Cn[n], acc);
    }
    float yv = fmaf(xv, Dv, acc) * szv;
    yp[(size_t)j * DI_] = __float2bfloat16(yv);
    xv = xn; szv = szn;
  }
}

// ---------------- final LN(token 0) + cls head + reg head ----------------
__global__ __launch_bounds__(192) void k_head(const float* __restrict__ t,
                                              const float* __restrict__ fn_g,
                                              const float* __restrict__ fn_b,
                                              const float* __restrict__ cls_w,
                                              const float* __restrict__ cls_b,
                                              const float* __restrict__ rw1,
                                              const float* __restrict__ rb1,
                                              const float* __restrict__ rw2,
                                              const float* __restrict__ rb2,
                                              float* __restrict__ out) {
  __shared__ float red[8];
  __shared__ float stats[2];
  __shared__ float feat_s[192];
  __shared__ float h_s[96];
  int b = blockIdx.x, tid = threadIdx.x;
  float x = t[(size_t)b * L_ * D_ + tid];
  float s = x, q = x * x;
#pragma unroll
  for (int off = 1; off < 64; off <<= 1) {
    s += __shfl_xor(s, off, 64);
    q += __shfl_xor(q, off, 64);
  }
  int w = tid >> 6;
  if ((tid & 63) == 0) { red[w] = s; red[4 + w] = q; }
  __syncthreads();
  if (tid == 0) {
    float ss = red[0] + red[1] + red[2];
    float qq = red[4] + red[5] + red[6];
    float m = ss * (1.f / 192.f);
    stats[0] = m;
    stats[1] = rsqrtf(qq * (1.f / 192.f) - m * m + 1e-5f);
  }
  __syncthreads();
  float fv = (x - stats[0]) * stats[1] * fn_g[tid] + fn_b[tid];
  feat_s[tid] = fv;
  __syncthreads();
  if (tid < 96) {
    float a = rb1[tid];
    const float* wr = rw1 + (size_t)tid * 192;
    for (int k = 0; k < 192; k++) a = fmaf(feat_s[k], wr[k], a);
    h_s[tid] = 0.5f * a * (1.f + erff(a * 0.70710678118654752f));
  } else if (tid < 98) {
    int c = tid - 96;
    float a = cls_b[c];
    const float* wr = cls_w + (size_t)c * 192;
    for (int k = 0; k < 192; k++) a = fmaf(feat_s[k], wr[k], a);
    out[b * 2 + c] = a;
  }
  __syncthreads();
  if (tid == 0) {
    float a = rb2[0];
    for (int j = 0; j < 96; j++) a = fmaf(h_s[j], rw2[j], a);
    out[64 + b] = a;
  }
}

extern "C" void kernel_launch(void* const* d_in, const int* in_sizes, int n_in,
                              void* d_out, int out_size, void* d_ws, size_t ws_size,
                              hipStream_t stream) {
  const float* x       = (const float*)d_in[0];
  const float* patch_w = (const float*)d_in[1];
  const float* patch_b = (const float*)d_in[2];
  const float* cls_tok = (const float*)d_in[3];
  const float* pos     = (const float*)d_in[4];
  const float* ln_g    = (const float*)d_in[5];
  const float* ln_b    = (const float*)d_in[6];
  const float* w_in    = (const float*)d_in[7];
  const float* conv_w  = (const float*)d_in[8];
  const float* conv_b  = (const float*)d_in[9];
  const float* w_x     = (const float*)d_in[10];
  const float* w_dt    = (const float*)d_in[11];
  const float* b_dt    = (const float*)d_in[12];
  const float* A_log   = (const float*)d_in[13];
  const float* D_ssm   = (const float*)d_in[14];
  const float* w_out   = (const float*)d_in[15];
  const float* fn_g    = (const float*)d_in[16];
  const float* fn_b    = (const float*)d_in[17];
  const float* cls_w   = (const float*)d_in[18];
  const float* cls_b   = (const float*)d_in[19];
  const float* reg_w1  = (const float*)d_in[20];
  const float* reg_b1  = (const float*)d_in[21];
  const float* reg_w2  = (const float*)d_in[22];
  const float* reg_b2  = (const float*)d_in[23];
  float* out = (float*)d_out;

  float* ws = (float*)d_ws;
  // workspace layout (floats)
  float* t_buf = ws;                        // 32*197*192 = 1,210,368
  float* xz    = t_buf + 1210368;           // 6304*768   = 4,841,472
  float* xa    = xz + 4841472;              // 6304*384   = 2,420,736
  float* szb   = xa + 2420736;              // 2,420,736
  float* bcd   = szb + 2420736;             // 6336*64    = 405,504
  float* Pst   = bcd + 405504;              // 32*8*384*16 = 1,572,864
  float* Hst   = Pst + 1572864;             // 1,572,864
  float* Hinit = Hst + 1572864;             // 1,572,864
  // bf16 region
  __hip_bfloat16* Abuf   = (__hip_bfloat16*)(Hinit + 1572864);  // 6272*768 = 4,816,896
  __hip_bfloat16* xa_bf  = Abuf;                 // alias (6336*384 = 2,433,024; Abuf dead by then)
  __hip_bfloat16* xln_bf = Abuf + 2433024;       // 6336*192 = 1,216,512 (fits in Abuf tail)
  __hip_bfloat16* y_bf   = Abuf + 4816896;       // 6336*384 = 2,433,024
  __hip_bfloat16* pw_bf  = y_bf + 2433024;       // 147,456
  __hip_bfloat16* win_bf = pw_bf + 147456;       // 589,824
  __hip_bfloat16* wout_bf = win_bf + 589824;     // 294,912
  __hip_bfloat16* wx_bf  = wout_bf + 294912;     // 4*64*384 = 98,304

  // weight casts (every call; same work each time)
  k_cast<<<256, 256, 0, stream>>>(patch_w, pw_bf, 147456);
  k_cast<<<256, 256, 0, stream>>>(w_in, win_bf, 589824);
  k_cast<<<256, 256, 0, stream>>>(w_out, wout_bf, 294912);
  k_cast_wx<<<384, 256, 0, stream>>>(w_x, wx_bf);

  k_cls<<<32, 192, 0, stream>>>(cls_tok, pos, t_buf);
  k_im2col<<<18816, 256, 0, stream>>>(x, Abuf);
  k_gemm_mfma<768, 2><<<dim3(98, 3), 256, 0, stream>>>(
      (const short*)Abuf, (const short*)pw_bf, t_buf, patch_b, pos, 6272);

  for (int i = 0; i < DEPTH_; i++) {
    k_ln_bf<<<B_ * L_, 64, 0, stream>>>(t_buf, ln_g + i * D_, ln_b + i * D_, xln_bf);
    k_gemm_mfma<192, 0><<<dim3(99, 12), 256, 0, stream>>>(
        (const short*)xln_bf, (const short*)(win_bf + (size_t)i * 147456), xz,
        nullptr, nullptr, 6304);
    k_conv<<<B_ * L_, 384, 0, stream>>>(xz, conv_w + i * DI_ * DC_, conv_b + i * DI_,
                                        xa, xa_bf, szb);
    k_gemm_mfma<384, 3><<<dim3(99, 1), 256, 0, stream>>>(
        (const short*)xa_bf, (const short*)(wx_bf + (size_t)i * 24576), bcd,
        nullptr, nullptr, 6304);
    k_scan1<<<B_ * NCH, 384, 0, stream>>>(xa, bcd, A_log + i * DI_ * DS_,
                                          w_dt + i * DI_, b_dt + i * DI_, Pst, Hst);
    k_scan_mid<<<768, 256, 0, stream>>>(Pst, Hst, Hinit);
    k_scan2<<<B_ * NCH, 384, 0, stream>>>(xa, szb, bcd, A_log + i * DI_ * DS_,
                                          D_ssm + i * DI_, w_dt + i * DI_, b_dt + i * DI_,
                                          Hinit, y_bf);
    k_gemm_mfma<384, 1><<<dim3(99, 3), 256, 0, stream>>>(
        (const short*)y_bf, (const short*)(wout_bf + (size_t)i * 73728), t_buf,
        nullptr, nullptr, 6304);
  }
  k_head<<<32, 192, 0, stream>>>(t_buf, fn_g, fn_b, cls_w, cls_b, reg_w1, reg_b1,
                                 reg_w2, reg_b2, out);
}

// Round 7
// 462.043 us; speedup vs baseline: 1.6214x; 1.1448x over previous
//
#include <hip/hip_runtime.h>
#include <hip/hip_bf16.h>
#include <math.h>

// Problem constants
#define B_ 32
#define D_ 192
#define DEPTH_ 4
#define DI_ 384
#define DS_ 16
#define DC_ 4
#define P_ 16
#define IMG_ 224
#define N_ 196
#define L_ 197

// scan chunking
#define NCH 16
#define CHL 13   // 16*13 = 208 >= 197

typedef short s16x8 __attribute__((ext_vector_type(8)));
typedef float f32x16 __attribute__((ext_vector_type(16)));

__device__ __forceinline__ float sigmoidf_(float x) { return 1.f / (1.f + expf(-x)); }

// ---------------- prep: weight casts + w_x pad + cls row + Aneg ----------------
__global__ __launch_bounds__(256) void k_prep(const float* __restrict__ patch_w,
                                              const float* __restrict__ w_in,
                                              const float* __restrict__ w_out,
                                              const float* __restrict__ w_x,
                                              const float* __restrict__ cls_tok,
                                              const float* __restrict__ pos,
                                              const float* __restrict__ A_log,
                                              __hip_bfloat16* __restrict__ pw,
                                              __hip_bfloat16* __restrict__ win,
                                              __hip_bfloat16* __restrict__ wout,
                                              __hip_bfloat16* __restrict__ wx,
                                              float* __restrict__ t,
                                              float* __restrict__ Aneg) {
  int idx = blockIdx.x * 256 + threadIdx.x;  // grid 4536 exact = 1,161,216
  if (idx < 147456) { pw[idx] = __float2bfloat16(patch_w[idx]); return; }
  idx -= 147456;
  if (idx < 589824) { win[idx] = __float2bfloat16(w_in[idx]); return; }
  idx -= 589824;
  if (idx < 294912) { wout[idx] = __float2bfloat16(w_out[idx]); return; }
  idx -= 294912;
  if (idx < 98304) {
    int li = idx / 24576;
    int r = (idx / 384) & 63;
    int c = idx % 384;
    wx[idx] = (r < 33) ? __float2bfloat16(w_x[(li * 33 + r) * 384 + c]) : __float2bfloat16(0.f);
    return;
  }
  idx -= 98304;
  if (idx < 6144) {
    int b = idx / 192, d = idx % 192;
    t[(size_t)b * L_ * D_ + d] = cls_tok[d] + pos[d];
    return;
  }
  idx -= 6144;
  Aneg[idx] = -expf(A_log[idx]);  // 24576
}

// ---------------- im2col: x (B,3,224,224) -> A bf16 (6272 x 768) ----------------
__global__ __launch_bounds__(256) void k_im2col(const float* __restrict__ x,
                                                __hip_bfloat16* __restrict__ A) {
  int idx = blockIdx.x * 256 + threadIdx.x;  // grid exact: 18816*256 = 6272*768
  int tok = idx / 768, f = idx - tok * 768;
  int b = tok / 196, p = tok - b * 196;
  int h = p / 14, w = p - h * 14;
  int c = f >> 8, i = (f >> 4) & 15, j = f & 15;
  float v = x[(((size_t)(b * 3 + c) * 224 + h * 16 + i) * 224 + w * 16 + j)];
  A[idx] = __float2bfloat16(v);
}

// ---------------- generic bf16 MFMA GEMM: C[M x N] = A[M x K] @ W[N x K]^T ----------------
// MODE 1: C fp32 (stride 192) += acc                 (t += y @ w_out^T)
// MODE 2: patch epilogue into t (fp32)
// MODE 3: C fp32 (stride 64) = acc                   (bcd = xa @ w_x_pad^T)
// MODE 4: C bf16 (stride 768) = acc                  (xz_bf = ln(t) @ w_in^T)
template <int KTOT, int MODE>
__global__ __launch_bounds__(256) void k_gemm_mfma(const short* __restrict__ A,
                                                   const short* __restrict__ Wb,
                                                   float* __restrict__ C,
                                                   const float* __restrict__ bias,
                                                   const float* __restrict__ pos,
                                                   int M) {
  constexpr int KC = 96;
  constexpr int STR = 104;  // 4-way worst-case bank conflict on b128 (1.58x) - acceptable
  __shared__ __align__(16) short Als[64 * STR];
  __shared__ __align__(16) short Bls[64 * STR];
  int m0 = blockIdx.x * 64, n0 = blockIdx.y * 64;
  int tid = threadIdx.x;
  int lane = tid & 63, wid = tid >> 6;
  int mw = (wid & 1) * 32, nw = (wid >> 1) * 32;
  int l31 = lane & 31, lh = lane >> 5;
  f32x16 acc;
#pragma unroll
  for (int i = 0; i < 16; i++) acc[i] = 0.f;
  for (int kc = 0; kc < KTOT; kc += KC) {
    __syncthreads();
#pragma unroll
    for (int i = 0; i < 3; i++) {
      int seg = tid + i * 256;        // 768 segments: 64 rows x 12 k-segs of 8 bf16
      int r = seg / 12, s = seg - r * 12;
      *(s16x8*)(Als + r * STR + s * 8) =
          *(const s16x8*)(A + (size_t)(m0 + r) * KTOT + kc + s * 8);
      *(s16x8*)(Bls + r * STR + s * 8) =
          *(const s16x8*)(Wb + (size_t)(n0 + r) * KTOT + kc + s * 8);
    }
    __syncthreads();
#pragma unroll
    for (int ks = 0; ks < KC / 16; ks++) {
      s16x8 af = *(const s16x8*)(Als + (mw + l31) * STR + ks * 16 + lh * 8);
      s16x8 bf = *(const s16x8*)(Bls + (nw + l31) * STR + ks * 16 + lh * 8);
      acc = __builtin_amdgcn_mfma_f32_32x32x16_bf16(af, bf, acc, 0, 0, 0);
    }
  }
  // epilogue: C/D layout col=lane&31, row=(reg&3)+8*(reg>>2)+4*(lane>>5)
  int gn = n0 + nw + l31;
#pragma unroll
  for (int i = 0; i < 16; i++) {
    int rowt = mw + (i & 3) + 8 * (i >> 2) + 4 * lh;
    int gm = m0 + rowt;
    float v = acc[i];
    if (MODE == 1) {
      if (gm < M) C[(size_t)gm * 192 + gn] += v;
    } else if (MODE == 3) {
      if (gm < M) C[(size_t)gm * 64 + gn] = v;
    } else if (MODE == 4) {
      if (gm < M) ((__hip_bfloat16*)C)[(size_t)gm * 768 + gn] = __float2bfloat16(v);
    } else {
      int b = gm / 196, p = gm - b * 196;
      C[((size_t)b * 197 + 1 + p) * 192 + gn] =
          v + bias[gn] + pos[(size_t)(1 + p) * 192 + gn];
    }
  }
}

// ---------------- LayerNorm, 4 tokens/block -> bf16 out ----------------
__global__ __launch_bounds__(256) void k_ln_bf(const float* __restrict__ t,
                                               const float* __restrict__ g,
                                               const float* __restrict__ bb,
                                               __hip_bfloat16* __restrict__ o) {
  int tok = blockIdx.x * 4 + (threadIdx.x >> 6);
  int tid = threadIdx.x & 63;
  const float* xr = t + (size_t)tok * D_;
  float x0 = xr[tid], x1 = xr[tid + 64], x2 = xr[tid + 128];
  float s = x0 + x1 + x2;
  float q = x0 * x0 + x1 * x1 + x2 * x2;
#pragma unroll
  for (int off = 1; off < 64; off <<= 1) {
    s += __shfl_xor(s, off, 64);
    q += __shfl_xor(q, off, 64);
  }
  float m = s * (1.f / 192.f);
  float r = rsqrtf(q * (1.f / 192.f) - m * m + 1e-5f);
  __hip_bfloat16* orow = o + (size_t)tok * D_;
  orow[tid]       = __float2bfloat16((x0 - m) * r * g[tid]       + bb[tid]);
  orow[tid + 64]  = __float2bfloat16((x1 - m) * r * g[tid + 64]  + bb[tid + 64]);
  orow[tid + 128] = __float2bfloat16((x2 - m) * r * g[tid + 128] + bb[tid + 128]);
}

// ---------------- causal depthwise conv + silu: 8 tokens/block, LDS window ----------------
__global__ __launch_bounds__(384) void k_conv(const __hip_bfloat16* __restrict__ xz,
                                              const float* __restrict__ cw_,
                                              const float* __restrict__ cb,
                                              __hip_bfloat16* __restrict__ xa_bf,
                                              __hip_bfloat16* __restrict__ sz_bf) {
  __shared__ float xs[11][384];
  int r0 = blockIdx.x * 8;  // 788 blocks * 8 = 6304
  int d = threadIdx.x;
#pragma unroll
  for (int row = 0; row < 11; row++) {
    int gr = r0 - 3 + row;
    if (gr >= 0) xs[row][d] = __bfloat162float(xz[(size_t)gr * 768 + d]);
  }
  __syncthreads();
  float4 cw = *(const float4*)(cw_ + d * 4);
  float cbv = cb[d];
#pragma unroll
  for (int tk = 0; tk < 8; tk++) {
    int tok = r0 + tk;
    int l = tok % L_;
    float acc = fmaf(cw.w, xs[tk + 3][d], cbv);
    if (l >= 1) acc = fmaf(cw.z, xs[tk + 2][d], acc);
    if (l >= 2) acc = fmaf(cw.y, xs[tk + 1][d], acc);
    if (l >= 3) acc = fmaf(cw.x, xs[tk][d], acc);
    float xav = acc * sigmoidf_(acc);
    xa_bf[(size_t)tok * DI_ + d] = __float2bfloat16(xav);
    float z = __bfloat162float(xz[(size_t)tok * 768 + 384 + d]);
    sz_bf[(size_t)tok * DI_ + d] = __float2bfloat16(z * sigmoidf_(z));
  }
}

// ---------------- selective scan, 3-phase chunked parallel scan ----------------
// bcd layout [tok][64]: 0..15 = B, 16..31 = C, 32 = dt raw. dt softplus inline.
__global__ __launch_bounds__(384) void k_scan1(const __hip_bfloat16* __restrict__ xa,
                                               const float* __restrict__ bcd,
                                               const float* __restrict__ Aneg,
                                               const float* __restrict__ w_dt,
                                               const float* __restrict__ b_dt,
                                               float* __restrict__ Pst,
                                               float* __restrict__ Hst) {
  int b = blockIdx.x >> 4, ch = blockIdx.x & 15;
  int d = threadIdx.x;
  int l0 = ch * CHL;
  int lim = min(CHL, L_ - l0);
  float Av[16];
#pragma unroll
  for (int q = 0; q < 4; q++) {
    float4 v = *(const float4*)(Aneg + d * 16 + q * 4);
    Av[q * 4] = v.x; Av[q * 4 + 1] = v.y; Av[q * 4 + 2] = v.z; Av[q * 4 + 3] = v.w;
  }
  float wdt = w_dt[d], bdt = b_dt[d];
  const __hip_bfloat16* xap = xa + ((size_t)b * L_ + l0) * DI_ + d;
  const float* bp = bcd + ((size_t)b * L_ + l0) * 64;
  float h[16], Pp[16];
#pragma unroll
  for (int n = 0; n < 16; n++) { h[n] = 0.f; Pp[n] = 1.f; }
  float xv = __bfloat162float(xap[0]);
  for (int j = 0; j < lim; j++) {
    int jn = (j + 1 < lim) ? (j + 1) : j;
    float xn = __bfloat162float(xap[(size_t)jn * DI_]);
    float dtraw = bp[j * 64 + 32];
    float Bn[16];
#pragma unroll
    for (int n = 0; n < 16; n++) Bn[n] = bp[j * 64 + n];   // block-uniform -> scalarized
    float v = fmaf(dtraw, wdt, bdt);
    float dtv = (v > 20.f) ? v : __logf(1.f + __expf(v));
    float dtx = dtv * xv;
#pragma unroll
    for (int n = 0; n < 16; n++) {
      float dA = __expf(dtv * Av[n]);
      h[n] = fmaf(dA, h[n], dtx * Bn[n]);
      Pp[n] *= dA;
    }
    xv = xn;
  }
  size_t s = ((size_t)blockIdx.x * 384 + d) * 16;
#pragma unroll
  for (int q = 0; q < 4; q++) {
    *(float4*)(Pst + s + q * 4) = make_float4(Pp[q * 4], Pp[q * 4 + 1], Pp[q * 4 + 2], Pp[q * 4 + 3]);
    *(float4*)(Hst + s + q * 4) = make_float4(h[q * 4], h[q * 4 + 1], h[q * 4 + 2], h[q * 4 + 3]);
  }
}

__global__ __launch_bounds__(256) void k_scan_mid(const float* __restrict__ Pst,
                                                  const float* __restrict__ Hst,
                                                  float* __restrict__ Hinit) {
  int idx = blockIdx.x * 256 + threadIdx.x;  // 768 blocks: 32*6144 = 196608
  int b = idx / 6144, r = idx - b * 6144;
  float h = 0.f;
#pragma unroll
  for (int c = 0; c < NCH; c++) {
    size_t o = (size_t)(b * NCH + c) * 6144 + r;
    Hinit[o] = h;
    h = fmaf(Pst[o], h, Hst[o]);
  }
}

__global__ __launch_bounds__(384) void k_scan2(const __hip_bfloat16* __restrict__ xa,
                                               const __hip_bfloat16* __restrict__ sz,
                                               const float* __restrict__ bcd,
                                               const float* __restrict__ Aneg,
                                               const float* __restrict__ D_ssm,
                                               const float* __restrict__ w_dt,
                                               const float* __restrict__ b_dt,
                                               const float* __restrict__ Hinit,
                                               __hip_bfloat16* __restrict__ y) {
  int b = blockIdx.x >> 4, ch = blockIdx.x & 15;
  int d = threadIdx.x;
  int l0 = ch * CHL;
  int lim = min(CHL, L_ - l0);
  float Av[16];
#pragma unroll
  for (int q = 0; q < 4; q++) {
    float4 v = *(const float4*)(Aneg + d * 16 + q * 4);
    Av[q * 4] = v.x; Av[q * 4 + 1] = v.y; Av[q * 4 + 2] = v.z; Av[q * 4 + 3] = v.w;
  }
  float Dv = D_ssm[d];
  float wdt = w_dt[d], bdt = b_dt[d];
  const __hip_bfloat16* xap = xa + ((size_t)b * L_ + l0) * DI_ + d;
  const __hip_bfloat16* szp = sz + ((size_t)b * L_ + l0) * DI_ + d;
  const float* bp = bcd + ((size_t)b * L_ + l0) * 64;
  __hip_bfloat16* yp = y + ((size_t)b * L_ + l0) * DI_ + d;
  float h[16];
  {
    size_t s = ((size_t)blockIdx.x * 384 + d) * 16;
#pragma unroll
    for (int q = 0; q < 4; q++) {
      float4 v = *(const float4*)(Hinit + s + q * 4);
      h[q * 4] = v.x; h[q * 4 + 1] = v.y; h[q * 4 + 2] = v.z; h[q * 4 + 3] = v.w;
    }
  }
  float xv = __bfloat162float(xap[0]);
  float szv = __bfloat162float(szp[0]);
  for (int j = 0; j < lim; j++) {
    int jn = (j + 1 < lim) ? (j + 1) : j;
    float xn = __bfloat162float(xap[(size_t)jn * DI_]);
    float szn = __bfloat162float(szp[(size_t)jn * DI_]);
    float dtraw = bp[j * 64 + 32];
    float Bn[16], Cn[16];
#pragma unroll
    for (int n = 0; n < 16; n++) Bn[n] = bp[j * 64 + n];
#pragma unroll
    for (int n = 0; n < 16; n++) Cn[n] = bp[j * 64 + 16 + n];
    float v = fmaf(dtraw, wdt, bdt);
    float dtv = (v > 20.f) ? v : __logf(1.f + __expf(v));
    float dtx = dtv * xv;
    float acc = 0.f;
#pragma unroll
    for (int n = 0; n < 16; n++) {
      float dA = __expf(dtv * Av[n]);
      h[n] = fmaf(dA, h[n], dtx * Bn[n]);
      acc = fmaf(h[n], Cn[n], acc);
    }
    float yv = fmaf(xv, Dv, acc) * szv;
    yp[(size_t)j * DI_] = __float2bfloat16(yv);
    xv = xn; szv = szn;
  }
}

// ---------------- final LN(token 0) + cls head + reg head ----------------
__global__ __launch_bounds__(192) void k_head(const float* __restrict__ t,
                                              const float* __restrict__ fn_g,
                                              const float* __restrict__ fn_b,
                                              const float* __restrict__ cls_w,
                                              const float* __restrict__ cls_b,
                                              const float* __restrict__ rw1,
                                              const float* __restrict__ rb1,
                                              const float* __restrict__ rw2,
                                              const float* __restrict__ rb2,
                                              float* __restrict__ out) {
  __shared__ float red[8];
  __shared__ float stats[2];
  __shared__ float feat_s[192];
  __shared__ float h_s[96];
  int b = blockIdx.x, tid = threadIdx.x;
  float x = t[(size_t)b * L_ * D_ + tid];
  float s = x, q = x * x;
#pragma unroll
  for (int off = 1; off < 64; off <<= 1) {
    s += __shfl_xor(s, off, 64);
    q += __shfl_xor(q, off, 64);
  }
  int w = tid >> 6;
  if ((tid & 63) == 0) { red[w] = s; red[4 + w] = q; }
  __syncthreads();
  if (tid == 0) {
    float ss = red[0] + red[1] + red[2];
    float qq = red[4] + red[5] + red[6];
    float m = ss * (1.f / 192.f);
    stats[0] = m;
    stats[1] = rsqrtf(qq * (1.f / 192.f) - m * m + 1e-5f);
  }
  __syncthreads();
  float fv = (x - stats[0]) * stats[1] * fn_g[tid] + fn_b[tid];
  feat_s[tid] = fv;
  __syncthreads();
  if (tid < 96) {
    float a = rb1[tid];
    const float* wr = rw1 + (size_t)tid * 192;
    for (int k = 0; k < 192; k++) a = fmaf(feat_s[k], wr[k], a);
    h_s[tid] = 0.5f * a * (1.f + erff(a * 0.70710678118654752f));
  } else if (tid < 98) {
    int c = tid - 96;
    float a = cls_b[c];
    const float* wr = cls_w + (size_t)c * 192;
    for (int k = 0; k < 192; k++) a = fmaf(feat_s[k], wr[k], a);
    out[b * 2 + c] = a;
  }
  __syncthreads();
  if (tid == 0) {
    float a = rb2[0];
    for (int j = 0; j < 96; j++) a = fmaf(h_s[j], rw2[j], a);
    out[64 + b] = a;
  }
}

extern "C" void kernel_launch(void* const* d_in, const int* in_sizes, int n_in,
                              void* d_out, int out_size, void* d_ws, size_t ws_size,
                              hipStream_t stream) {
  const float* x       = (const float*)d_in[0];
  const float* patch_w = (const float*)d_in[1];
  const float* patch_b = (const float*)d_in[2];
  const float* cls_tok = (const float*)d_in[3];
  const float* pos     = (const float*)d_in[4];
  const float* ln_g    = (const float*)d_in[5];
  const float* ln_b    = (const float*)d_in[6];
  const float* w_in    = (const float*)d_in[7];
  const float* conv_w  = (const float*)d_in[8];
  const float* conv_b  = (const float*)d_in[9];
  const float* w_x     = (const float*)d_in[10];
  const float* w_dt    = (const float*)d_in[11];
  const float* b_dt    = (const float*)d_in[12];
  const float* A_log   = (const float*)d_in[13];
  const float* D_ssm   = (const float*)d_in[14];
  const float* w_out   = (const float*)d_in[15];
  const float* fn_g    = (const float*)d_in[16];
  const float* fn_b    = (const float*)d_in[17];
  const float* cls_w   = (const float*)d_in[18];
  const float* cls_b   = (const float*)d_in[19];
  const float* reg_w1  = (const float*)d_in[20];
  const float* reg_b1  = (const float*)d_in[21];
  const float* reg_w2  = (const float*)d_in[22];
  const float* reg_b2  = (const float*)d_in[23];
  float* out = (float*)d_out;

  float* ws = (float*)d_ws;
  // fp32 region (floats)
  float* t_buf = ws;                         // 1,210,368
  float* bcd   = t_buf + 1210368;            // 6336*64 = 405,504
  float* Pst   = bcd + 405504;               // 32*16*6144 = 3,145,728
  float* Hst   = Pst + 3145728;              // 3,145,728
  float* Hinit = Hst + 3145728;              // 3,145,728
  float* Aneg  = Hinit + 3145728;            // 4*6144 = 24,576
  // bf16 region
  __hip_bfloat16* xz_bf  = (__hip_bfloat16*)(Aneg + 24576);  // 6304*768 = 4,841,472
  __hip_bfloat16* Abuf   = xz_bf;            // alias: im2col output, dead after patch gemm
  __hip_bfloat16* xa_bf  = xz_bf + 4841472;  // 6336*384 = 2,433,024
  __hip_bfloat16* sz_bf  = xa_bf + 2433024;  // 2,433,024
  __hip_bfloat16* xln_bf = sz_bf + 2433024;  // 6336*192 = 1,216,512
  __hip_bfloat16* y_bf   = xln_bf + 1216512; // 2,433,024
  __hip_bfloat16* pw_bf  = y_bf + 2433024;   // 147,456
  __hip_bfloat16* win_bf = pw_bf + 147456;   // 589,824
  __hip_bfloat16* wout_bf = win_bf + 589824; // 294,912
  __hip_bfloat16* wx_bf  = wout_bf + 294912; // 98,304

  k_prep<<<4536, 256, 0, stream>>>(patch_w, w_in, w_out, w_x, cls_tok, pos, A_log,
                                   pw_bf, win_bf, wout_bf, wx_bf, t_buf, Aneg);
  k_im2col<<<18816, 256, 0, stream>>>(x, Abuf);
  k_gemm_mfma<768, 2><<<dim3(98, 3), 256, 0, stream>>>(
      (const short*)Abuf, (const short*)pw_bf, t_buf, patch_b, pos, 6272);

  for (int i = 0; i < DEPTH_; i++) {
    k_ln_bf<<<1576, 256, 0, stream>>>(t_buf, ln_g + i * D_, ln_b + i * D_, xln_bf);
    k_gemm_mfma<192, 4><<<dim3(99, 12), 256, 0, stream>>>(
        (const short*)xln_bf, (const short*)(win_bf + (size_t)i * 147456), (float*)xz_bf,
        nullptr, nullptr, 6304);
    k_conv<<<788, 384, 0, stream>>>(xz_bf, conv_w + i * DI_ * DC_, conv_b + i * DI_,
                                    xa_bf, sz_bf);
    k_gemm_mfma<384, 3><<<dim3(99, 1), 256, 0, stream>>>(
        (const short*)xa_bf, (const short*)(wx_bf + (size_t)i * 24576), bcd,
        nullptr, nullptr, 6304);
    k_scan1<<<B_ * NCH, 384, 0, stream>>>(xa_bf, bcd, Aneg + i * 6144,
                                          w_dt + i * DI_, b_dt + i * DI_, Pst, Hst);
    k_scan_mid<<<768, 256, 0, stream>>>(Pst, Hst, Hinit);
    k_scan2<<<B_ * NCH, 384, 0, stream>>>(xa_bf, sz_bf, bcd, Aneg + i * 6144,
                                          D_ssm + i * DI_, w_dt + i * DI_, b_dt + i * DI_,
                                          Hinit, y_bf);
    k_gemm_mfma<384, 1><<<dim3(99, 3), 256, 0, stream>>>(
        (const short*)y_bf, (const short*)(wout_bf + (size_t)i * 73728), t_buf,
        nullptr, nullptr, 6304);
  }
  k_head<<<32, 192, 0, stream>>>(t_buf, fn_g, fn_b, cls_w, cls_b, reg_w1, reg_b1,
                                 reg_w2, reg_b2, out);
}